// Round 9
// baseline (273.471 us; speedup 1.0000x reference)
//
#include <hip/hip_runtime.h>

// RNN: B=2048 chains, T=1024 steps, H=64, I=1. One wave per chain,
// 2048 blocks (2 waves/SIMD TLP -- r7 showed this beats 1-wave ILP).
//
// Round-9: round-8 structure with the row_ror direction corrected.
// DPP row_ror:n sources lane (i-n) mod 16 (same direction as row_shr,
// cf. prefix-scan idiom), so at rotation j lane bq sees the h-pair of
// row-lane c = (bq - 2j) & 15. W columns now loaded to match.
//
// h lives in registers, distributed: lane (a=lane>>4, bq=lane&15) holds
// h[4bq+a]. Row a owns k-residues {k === a mod 4}; k-sweep = 7 row_ror
// DPP movs + 1 quad_perm (VALU only). Outputs 4bq+(s^a) in XOR slots;
// cross-row reduction = XOR butterfly reduce-scatter (ds_swizzle ^16,
// shfl ^32) landing h_new[4bq+a] at its home lane. Zero LDS h traffic.

constexpr int T_STEPS = 1024;
constexpr int H = 64;

typedef float v2f __attribute__((ext_vector_type(2)));
typedef float v4f __attribute__((ext_vector_type(4)));

template <int CTRL>
__device__ __forceinline__ float dpp_movf(float x) {
    return __builtin_bit_cast(float,
        __builtin_amdgcn_mov_dpp(__builtin_bit_cast(int, x), CTRL, 0xF, 0xF, true));
}

template <int J>
__device__ __forceinline__ v2f ror2(v2f p) {
    constexpr int ctrl = 0x120 + 2 * J;      // row_ror:2J (16-lane rows)
    v2f r;
    r.x = dpp_movf<ctrl>(p.x);
    r.y = dpp_movf<ctrl>(p.y);
    return r;
}

__device__ __forceinline__ float swz16(float x) {
    // ds_swizzle xor lane^16 (BitMode 0x401F); DS pipe, no LDS banks.
    return __builtin_bit_cast(float,
        __builtin_amdgcn_ds_swizzle(__builtin_bit_cast(int, x), 0x401F));
}

__device__ __forceinline__ float tanh_fast(float s) {
    // tanh(s) = 1 - 2/(exp2(s*2log2e)+1); saturates correctly at +-1.
    const float e = __builtin_amdgcn_exp2f(s * 2.88539008177792681472f);
    return 1.f - 2.f * __builtin_amdgcn_rcpf(e + 1.f);
}

__global__
__attribute__((amdgpu_flat_work_group_size(64, 64), amdgpu_waves_per_eu(2, 2)))
void rnn_fused(
    const float* __restrict__ x,      // [B, T, 1]
    const float* __restrict__ W_ih,   // [H, 1]
    const float* __restrict__ W_hh,   // [H, H] row-major
    const float* __restrict__ b_ih,   // [H]
    const float* __restrict__ b_hh,   // [H]
    const float* __restrict__ W_out,  // [1, H]
    const float* __restrict__ b_out,  // [1]
    float* __restrict__ out)          // [B, 1]
{
    const int bidx = blockIdx.x;
    const int lane = threadIdx.x;     // 0..63
    const int a    = lane >> 4;       // DPP row / k-residue class
    const int bq   = lane & 15;       // position within row
    const int pi   = 4 * bq + a;      // my output index (resident h index)

    __shared__ v4f xs4[T_STEPS / 4];  // 4 KiB: x[bidx, :]

    // Stage x[bidx, :], coalesced float4.
    const v4f* xrow = reinterpret_cast<const v4f*>(x + (size_t)bidx * T_STEPS);
    #pragma unroll
    for (int k = 0; k < T_STEPS / 4 / 64; ++k)
        xs4[lane + 64 * k] = xrow[lane + 64 * k];

    // W slots: slot s accumulates output o_s = 4bq + (s^a).
    // row_ror:2j sources lane (bq - 2j) & 15, so at rotation j this lane
    // sees the h-pair of row-lane c = (bq - 2j) & 15:
    //   ( h[4c+a], h[4(c^1)+a] )  -> matching W pair below.
    v2f w2[4][8];
    #pragma unroll
    for (int s = 0; s < 4; ++s) {
        const int o = 4 * bq + (s ^ a);
        const float* wr = W_hh + (size_t)o * H;
        #pragma unroll
        for (int j = 0; j < 8; ++j) {
            const int c = (bq - 2 * j) & 15;          // <-- direction fix
            w2[s][j] = v2f{wr[4 * c + a], wr[4 * (c ^ 1) + a]};
        }
    }
    #pragma unroll
    for (int s = 0; s < 4; ++s)
        #pragma unroll
        for (int j = 0; j < 8; ++j)
            asm volatile("" : "+v"(w2[s][j]));   // keep in arch VGPRs

    // Per-lane scalars for output pi.
    const float wihp  = W_ih[pi];
    const float biasp = b_ih[pi] + b_hh[pi];
    const float woutp = W_out[pi];

    float hn = 0.f;                   // resident h[pi]; h0 = 0

    auto step = [&](float xv) {
        const float seed = fmaf(xv, wihp, biasp);
        // pair (own, lane^1's h) via quad_perm [1,0,3,2]
        v2f p0;
        p0.x = hn;
        p0.y = dpp_movf<0xB1>(hn);
        v2f acc0 = __builtin_elementwise_fma(p0, w2[0][0], v2f{seed, 0.f});
        v2f acc1 = p0 * w2[1][0];
        v2f acc2 = p0 * w2[2][0];
        v2f acc3 = p0 * w2[3][0];
        #define ROT_ACC(J)                                                  \
        {                                                                   \
            const v2f pj = ror2<J>(p0);                                     \
            acc0 = __builtin_elementwise_fma(pj, w2[0][J], acc0);           \
            acc1 = __builtin_elementwise_fma(pj, w2[1][J], acc1);           \
            acc2 = __builtin_elementwise_fma(pj, w2[2][J], acc2);           \
            acc3 = __builtin_elementwise_fma(pj, w2[3][J], acc3);           \
        }
        ROT_ACC(1) ROT_ACC(2) ROT_ACC(3) ROT_ACC(4)
        ROT_ACC(5) ROT_ACC(6) ROT_ACC(7)
        #undef ROT_ACC
        const float m0 = acc0.x + acc0.y;
        const float m1 = acc1.x + acc1.y;
        const float m2 = acc2.x + acc2.y;
        const float m3 = acc3.x + acc3.y;
        // XOR butterfly reduce-scatter:
        // stage ^16: partner row a^1, its slot (s^1) holds my slot-s output.
        const float r0 = m0 + swz16(m1);
        const float r2 = m2 + swz16(m3);
        // stage ^32: partner row a^2, its r2 holds my slot-0 output.
        const float t = r0 + __shfl_xor(r2, 32);
        hn = tanh_fast(t);            // = h_new[pi], already at its home lane
    };

    #pragma unroll 1
    for (int t4 = 0; t4 < T_STEPS / 4; ++t4) {
        const v4f xq = xs4[t4];       // uniform ds_read_b128
        step(xq.x);
        step(xq.y);
        step(xq.z);
        step(xq.w);
    }

    // out = sigmoid(sum_i h[i] * W_out[i] + b_out); pi is a bijection of
    // lanes, so a full-wave sum covers all 64 outputs.
    float p = hn * woutp;
    #pragma unroll
    for (int off = 1; off <= 32; off <<= 1)
        p += __shfl_xor(p, off);
    if (lane == 0)
        out[bidx] = 1.f / (1.f + __expf(-(p + b_out[0])));
}

extern "C" void kernel_launch(void* const* d_in, const int* in_sizes, int n_in,
                              void* d_out, int out_size, void* d_ws, size_t ws_size,
                              hipStream_t stream)
{
    const float* x     = (const float*)d_in[0];
    const float* W_ih  = (const float*)d_in[1];
    const float* W_hh  = (const float*)d_in[2];
    const float* b_ih  = (const float*)d_in[3];
    const float* b_hh  = (const float*)d_in[4];
    const float* W_out = (const float*)d_in[5];
    const float* b_out = (const float*)d_in[6];
    float* out = (float*)d_out;

    const int B = out_size;           // one wave per chain
    rnn_fused<<<B, 64, 0, stream>>>(x, W_ih, W_hh, b_ih, b_hh, W_out, b_out, out);
}

// Round 11
// 250.697 us; speedup vs baseline: 1.0908x; 1.0908x over previous
//
#include <hip/hip_runtime.h>

// RNN: B=2048 chains, T=1024 steps, H=64, I=1. One wave per chain,
// 2048 blocks (2 waves/SIMD TLP).
//
// Round-11 = round-10 + bit_cast fix (cvt_pkrtz returns __fp16x2, fdot2
// wants _Float16x2; clang won't implicitly convert).
//
// Theory: fp32 VALU was the wrong pipe -- v_pk_fma_f32 is half-rate on
// CDNA4, so the fp32 MAC floor is 128 cyc/wave-step. v_dot2_f32_f16
// (__builtin_amdgcn_fdot2) is FULL rate: 2 f16 MACs / 2 cyc with fp32
// accumulate -> 32 instr/step for the 64 MACs, 7 dpp for the k-sweep
// (packed pairs rotate as one register), no merge adds.
// Precision: h,W in f16, fp32 accumulation, fp32 tanh state -> output
// error ~2e-4 << 1.2e-2 threshold.
//
// Layout (r9-verified): lane (a=lane>>4, bq=lane&15) holds h[4bq+a].
// Slot s accumulates output 4bq+(s^a). row_ror:2j sources lane (bq-2j)&15.
// Reduce-scatter: ds_swizzle ^16, shfl ^32 (r9-verified algebra).

constexpr int T_STEPS = 1024;
constexpr int H = 64;

typedef float v4f __attribute__((ext_vector_type(4)));
typedef _Float16 h2 __attribute__((ext_vector_type(2)));

template <int CTRL>
__device__ __forceinline__ h2 dpp_movh2(h2 x) {
    return __builtin_bit_cast(h2,
        __builtin_amdgcn_mov_dpp(__builtin_bit_cast(int, x), CTRL, 0xF, 0xF, true));
}
template <int CTRL>
__device__ __forceinline__ float dpp_movf(float x) {
    return __builtin_bit_cast(float,
        __builtin_amdgcn_mov_dpp(__builtin_bit_cast(int, x), CTRL, 0xF, 0xF, true));
}

__device__ __forceinline__ float swz16(float x) {
    // ds_swizzle xor lane^16 (BitMode 0x401F); DS pipe, no LDS banks.
    return __builtin_bit_cast(float,
        __builtin_amdgcn_ds_swizzle(__builtin_bit_cast(int, x), 0x401F));
}

__device__ __forceinline__ float tanh_fast(float s) {
    // tanh(s) = 1 - 2/(exp2(s*2log2e)+1); saturates correctly at +-1.
    const float e = __builtin_amdgcn_exp2f(s * 2.88539008177792681472f);
    return 1.f - 2.f * __builtin_amdgcn_rcpf(e + 1.f);
}

__global__
__attribute__((amdgpu_flat_work_group_size(64, 64), amdgpu_waves_per_eu(2, 2)))
void rnn_fused(
    const float* __restrict__ x,      // [B, T, 1]
    const float* __restrict__ W_ih,   // [H, 1]
    const float* __restrict__ W_hh,   // [H, H] row-major
    const float* __restrict__ b_ih,   // [H]
    const float* __restrict__ b_hh,   // [H]
    const float* __restrict__ W_out,  // [1, H]
    const float* __restrict__ b_out,  // [1]
    float* __restrict__ out)          // [B, 1]
{
    const int bidx = blockIdx.x;
    const int lane = threadIdx.x;     // 0..63
    const int a    = lane >> 4;       // DPP row / k-residue class
    const int bq   = lane & 15;       // position within row
    const int pi   = 4 * bq + a;      // my output index (resident h index)

    __shared__ v4f xs4[T_STEPS / 4];  // 4 KiB: x[bidx, :]

    // Stage x[bidx, :], coalesced float4.
    const v4f* xrow = reinterpret_cast<const v4f*>(x + (size_t)bidx * T_STEPS);
    #pragma unroll
    for (int k = 0; k < T_STEPS / 4 / 64; ++k)
        xs4[lane + 64 * k] = xrow[lane + 64 * k];

    // W as packed f16 pairs (RNE converts at init). Slot s = output
    // o_s = 4bq+(s^a); rotation j sees h-pair of lane c=(bq-2j)&15:
    // ( h[4c+a], h[4(c^1)+a] ).
    h2 w2[4][8];
    #pragma unroll
    for (int s = 0; s < 4; ++s) {
        const int o = 4 * bq + (s ^ a);
        const float* wr = W_hh + (size_t)o * H;
        #pragma unroll
        for (int j = 0; j < 8; ++j) {
            const int c = (bq - 2 * j) & 15;
            w2[s][j] = h2{(_Float16)wr[4 * c + a], (_Float16)wr[4 * (c ^ 1) + a]};
        }
    }
    #pragma unroll
    for (int s = 0; s < 4; ++s)
        #pragma unroll
        for (int j = 0; j < 8; ++j)
            asm volatile("" : "+v"(w2[s][j]));   // keep in arch VGPRs

    // Per-lane scalars for output pi (fp32 path).
    const float wihp  = W_ih[pi];
    const float biasp = b_ih[pi] + b_hh[pi];
    const float woutp = W_out[pi];

    float hn = 0.f;                   // resident h[pi] in fp32; h0 = 0

    auto step = [&](float xv) {
        const float seed = fmaf(xv, wihp, biasp);
        // pack (own, ^1-partner) as f16x2: 1 dpp + 1 cvt_pkrtz.
        const float hp = dpp_movf<0xB1>(hn);          // quad_perm [1,0,3,2]
        const h2 p0 = __builtin_bit_cast(h2, __builtin_amdgcn_cvt_pkrtz(hn, hp));
        // 32 full-rate fdot2: 4 slots x 8 rotations (dep chains of 8).
        float m0 = __builtin_amdgcn_fdot2(p0, w2[0][0], seed, false);
        float m1 = __builtin_amdgcn_fdot2(p0, w2[1][0], 0.f, false);
        float m2 = __builtin_amdgcn_fdot2(p0, w2[2][0], 0.f, false);
        float m3 = __builtin_amdgcn_fdot2(p0, w2[3][0], 0.f, false);
        #define ROT_ACC(J)                                              \
        {                                                               \
            const h2 pj = dpp_movh2<0x120 + 2 * (J)>(p0);               \
            m0 = __builtin_amdgcn_fdot2(pj, w2[0][J], m0, false);       \
            m1 = __builtin_amdgcn_fdot2(pj, w2[1][J], m1, false);       \
            m2 = __builtin_amdgcn_fdot2(pj, w2[2][J], m2, false);       \
            m3 = __builtin_amdgcn_fdot2(pj, w2[3][J], m3, false);       \
        }
        ROT_ACC(1) ROT_ACC(2) ROT_ACC(3) ROT_ACC(4)
        ROT_ACC(5) ROT_ACC(6) ROT_ACC(7)
        #undef ROT_ACC
        // XOR butterfly reduce-scatter (r9-verified):
        // ^16: partner row a^1, its slot s^1 matches my slot s's output.
        const float r0 = m0 + swz16(m1);
        const float r2 = m2 + swz16(m3);
        // ^32: partner row a^2, its r2 matches my r0's output.
        const float t = r0 + __shfl_xor(r2, 32);
        hn = tanh_fast(t);            // = h_new[pi], fp32, at its home lane
    };

    #pragma unroll 1
    for (int t4 = 0; t4 < T_STEPS / 4; ++t4) {
        const v4f xq = xs4[t4];       // uniform ds_read_b128
        step(xq.x);
        step(xq.y);
        step(xq.z);
        step(xq.w);
    }

    // out = sigmoid(sum_i h[i] * W_out[i] + b_out); pi is a bijection of
    // lanes, so a full-wave sum covers all 64 outputs. fp32 throughout.
    float p = hn * woutp;
    #pragma unroll
    for (int off = 1; off <= 32; off <<= 1)
        p += __shfl_xor(p, off);
    if (lane == 0)
        out[bidx] = 1.f / (1.f + __expf(-(p + b_out[0])));
}

extern "C" void kernel_launch(void* const* d_in, const int* in_sizes, int n_in,
                              void* d_out, int out_size, void* d_ws, size_t ws_size,
                              hipStream_t stream)
{
    const float* x     = (const float*)d_in[0];
    const float* W_ih  = (const float*)d_in[1];
    const float* W_hh  = (const float*)d_in[2];
    const float* b_ih  = (const float*)d_in[3];
    const float* b_hh  = (const float*)d_in[4];
    const float* W_out = (const float*)d_in[5];
    const float* b_out = (const float*)d_in[6];
    float* out = (float*)d_out;

    const int B = out_size;           // one wave per chain
    rnn_fused<<<B, 64, 0, stream>>>(x, W_ih, W_hh, b_ih, b_hh, W_out, b_out, out);
}